// Round 13
// baseline (1171.883 us; speedup 1.0000x reference)
//
#include <hip/hip_runtime.h>
#include <math.h>

#define B_ 32
#define T_ 1024
#define F_ 64
#define H_ 128
#define D_ 192
#define KH_ 16
#define C1_ 128
#define C2_ 256
#define C3_ 128
#define NC_ 10

typedef float v2f __attribute__((ext_vector_type(2)));
typedef float f32x4 __attribute__((ext_vector_type(4)));
typedef __bf16 bfrag __attribute__((ext_vector_type(8)));

__device__ __forceinline__ float sig_(float x){ return 1.f/(1.f+__expf(-x)); }
__device__ __forceinline__ float tanh_(float x){ return 1.f - 2.f/(__expf(2.f*x)+1.f); }
__device__ __forceinline__ float gelu_(float x){ return 0.5f*x*(1.f+erff(x*0.70710678118654752f)); }
__device__ __forceinline__ float softplus_(float x){ return fmaxf(x,0.f) + log1pf(__expf(-fabsf(x))); }

__device__ __forceinline__ unsigned bfpack(float a, float b){
  unsigned ua = __float_as_uint(a), ub = __float_as_uint(b);
  ua = ua + 0x7FFFu + ((ua>>16)&1u);
  ub = ub + 0x7FFFu + ((ub>>16)&1u);
  return (ua>>16) | (ub & 0xFFFF0000u);
}
__device__ __forceinline__ unsigned short bf1(float a){
  unsigned ua = __float_as_uint(a);
  ua = ua + 0x7FFFu + ((ua>>16)&1u);
  return (unsigned short)(ua>>16);
}
__device__ __forceinline__ float bf2f(unsigned short h){
  return __uint_as_float(((unsigned)h)<<16);
}

#define QPERM_XOR1(x) __int_as_float(__builtin_amdgcn_mov_dpp(__float_as_int(x), 0xB1, 0xF, 0xF, true))
#define QPERM_XOR2(x) __int_as_float(__builtin_amdgcn_mov_dpp(__float_as_int(x), 0x4E, 0xF, 0xF, true))

#define LDS_BARRIER() asm volatile("s_waitcnt lgkmcnt(0)\n\ts_barrier" ::: "memory")

// ================================================================ bodies

// ---- ax precompute (transposed out: axT[b][j][t])
__device__ __forceinline__ void ax_body(int blk, char* smemraw,
    const float* __restrict__ x, const float* __restrict__ w1, const float* __restrict__ b1,
    float* __restrict__ axT)
{
  struct AxS { float xs[16][68]; float w1s[64][16]; };
  AxS* sm = (AxS*)smemraw;
  const int bt0 = blk*16;
  const int tid = threadIdx.x;
  for(int i=tid;i<64*16;i+=256){ sm->w1s[i>>4][i&15] = w1[i]; }
  for(int i=tid;i<16*64;i+=256){ const int r=i>>6, d=i&63; sm->xs[r][d] = x[(size_t)(bt0+r)*64 + d]; }
  __syncthreads();
  const int r = tid>>4, j = tid&15;
  float s = b1[j];
  #pragma unroll
  for(int d=0; d<64; d++) s += sm->xs[r][d]*sm->w1s[d][j];
  const int bt = bt0 + r;
  axT[((size_t)(bt>>10)*16 + j)*1024 + (bt&1023)] = s;
}

// ---- weight prepack (bf16 MFMA B-fragment blocks, all 3 convs)
__device__ __forceinline__ void prepack_body(int blk,
    const float* __restrict__ w1s, const float* __restrict__ w2s, const float* __restrict__ w3s,
    unsigned short* __restrict__ wp1, unsigned short* __restrict__ wp2, unsigned short* __restrict__ wp3)
{
  int e = blk*256 + threadIdx.x;
  if(e >= 65536+163840+98304) return;
  const float* w; unsigned short* wp; int Cout, Cin, Kw;
  if(e < 65536){ w=w1s; wp=wp1; Cout=C1_; Cin=F_;  Kw=8; }
  else if(e < 65536+163840){ e-=65536; w=w2s; wp=wp2; Cout=C2_; Cin=C1_; Kw=5; }
  else { e-=229376; w=w3s; wp=wp3; Cout=C3_; Cin=C2_; Kw=3; }
  const int co = e/(Cin*Kw);
  const int rem = e - co*(Cin*Kw);
  const int ci = rem/Kw, kw = rem - ci*Kw;
  const int off = (((ci>>5)*Kw + kw)*(Cout>>4) + (co>>4))*512 + ((co&15)*4 + ((ci>>3)&3))*8 + (ci&7);
  wp[off] = bf1(w[e]);
}

// ---- LSTM scan body (R10 numerics; 256-thread block, upper half joins barriers only)
__device__ __forceinline__ void lstm_body(int b, char* smemraw,
    const float* __restrict__ axT, const float* __restrict__ w1,
    const float* __restrict__ w2, const float* __restrict__ b2,
    float* __restrict__ hidden)
{
  float* hsall = (float*)smemraw;   // [2][148]
  const int tid = threadIdx.x;
  const bool act = tid < 128;
  const int l = tid & 63, wv = (tid >> 6) & 1;
  const int j = l >> 2, g = l & 3;
  const int hi = wv*64 + l;

  v2f w1hv[16]; v2f w2if[16], w2go[16]; v2f bif, bgo;
  if(act){
    #pragma unroll
    for(int q=0;q<16;q++){
      w1hv[q].x = w1[(64 + g*32 + 2*q)*KH_ + j];
      w1hv[q].y = w1[(64 + g*32 + 2*q + 1)*KH_ + j];
    }
    #pragma unroll
    for(int k=0;k<16;k++){
      w2if[k].x = w2[k*512 + hi];       w2if[k].y = w2[k*512 + 128 + hi];
      w2go[k].x = w2[k*512 + 256 + hi]; w2go[k].y = w2[k*512 + 384 + hi];
    }
    bif.x = b2[hi]; bif.y = b2[128+hi]; bgo.x = b2[256+hi]; bgo.y = b2[384+hi];
  }

  for(int i=tid;i<2*148;i+=256) hsall[i]=0.f;
  float c = 0.f;
  const float* axr = axT + ((size_t)b*16 + j)*1024;
  float* hb = hidden + (size_t)b*T_*H_;
  const int hwi = (hi>>5)*36 + (hi&31);
  float4 axA, axB;
  if(act){ axA = *(const float4*)&axr[0]; axB = *(const float4*)&axr[4]; }
  __syncthreads();

#define LSTM_STEP(tt, axv, RB) { \
    if(act){ \
      const float* hsr = hsall + (RB)*148; \
      float* hsw = hsall + (1-(RB))*148; \
      v2f ap0=(v2f)(0.f), ap1=(v2f)(0.f), ap2=(v2f)(0.f), ap3=(v2f)(0.f); \
      { const float4 hv = *(const float4*)&hsr[g*36 + 0];  ap0 += ((v2f){hv.x,hv.y})*w1hv[0]  + ((v2f){hv.z,hv.w})*w1hv[1]; } \
      { const float4 hv = *(const float4*)&hsr[g*36 + 4];  ap1 += ((v2f){hv.x,hv.y})*w1hv[2]  + ((v2f){hv.z,hv.w})*w1hv[3]; } \
      { const float4 hv = *(const float4*)&hsr[g*36 + 8];  ap2 += ((v2f){hv.x,hv.y})*w1hv[4]  + ((v2f){hv.z,hv.w})*w1hv[5]; } \
      { const float4 hv = *(const float4*)&hsr[g*36 + 12]; ap3 += ((v2f){hv.x,hv.y})*w1hv[6]  + ((v2f){hv.z,hv.w})*w1hv[7]; } \
      { const float4 hv = *(const float4*)&hsr[g*36 + 16]; ap0 += ((v2f){hv.x,hv.y})*w1hv[8]  + ((v2f){hv.z,hv.w})*w1hv[9]; } \
      { const float4 hv = *(const float4*)&hsr[g*36 + 20]; ap1 += ((v2f){hv.x,hv.y})*w1hv[10] + ((v2f){hv.z,hv.w})*w1hv[11]; } \
      { const float4 hv = *(const float4*)&hsr[g*36 + 24]; ap2 += ((v2f){hv.x,hv.y})*w1hv[12] + ((v2f){hv.z,hv.w})*w1hv[13]; } \
      { const float4 hv = *(const float4*)&hsr[g*36 + 28]; ap3 += ((v2f){hv.x,hv.y})*w1hv[14] + ((v2f){hv.z,hv.w})*w1hv[15]; } \
      const v2f apt = (ap0+ap1)+(ap2+ap3); \
      float a = apt.x + apt.y; \
      a += QPERM_XOR1(a); \
      a += QPERM_XOR2(a); \
      a += (axv); \
      const float g1 = a * sig_(a); \
      v2f aIF = bif, aGO = bgo; \
      _Pragma("unroll") \
      for(int k=0;k<16;k++){ \
        const float gk = __int_as_float(__builtin_amdgcn_readlane(__float_as_int(g1), 4*k)); \
        v2f gk2; gk2.x=gk; gk2.y=gk; \
        aIF += gk2 * w2if[k]; \
        aGO += gk2 * w2go[k]; \
      } \
      const float si = sig_(aIF.x); \
      const float sf = sig_(aIF.y); \
      const float tg = tanh_(aGO.x); \
      const float so = sig_(aGO.y); \
      c = sf*c + si*tg; \
      const float h = so * tanh_(c); \
      hsw[hwi] = h; \
      hb[(size_t)(tt)*H_ + hi] = h; \
    } \
    LDS_BARRIER(); \
  }

  for(int t0=0;t0<T_;t0+=4){
    const int tl = (t0+8 < 1020) ? (t0+8) : 1020;
    float4 axC;
    if(act) axC = *(const float4*)&axr[tl];
    LSTM_STEP(t0+0, axA.x, 0)
    LSTM_STEP(t0+1, axA.y, 1)
    LSTM_STEP(t0+2, axA.z, 0)
    LSTM_STEP(t0+3, axA.w, 1)
    if(act){ axA = axB; axB = axC; }
  }
#undef LSTM_STEP
}

// ---- row norms
__device__ __forceinline__ void norm_body(int blk,
    const float* __restrict__ hidden, float* __restrict__ norms)
{
  const int row = blk*8 + (threadIdx.x>>5);
  const int l = threadIdx.x&31;
  const float* hr = hidden + (size_t)row*H_;
  float s = 0.f;
  for(int k=l;k<H_;k+=32){ float v=hr[k]; s+=v*v; }
  #pragma unroll
  for(int m=16;m>=1;m>>=1) s += __shfl_xor(s, m, 64);
  if(l==0) norms[row] = fmaxf(sqrtf(s), 1e-8f);
}

// ---- S rowsums via bf16 MFMA (hi/lo split Gram)
struct SS {
  unsigned short Ahi[64*136];
  unsigned short Alo[64*136];
  unsigned short Bhi[64*136];
  unsigned short Blo[64*136];
  double red[64][17];
};
__device__ __forceinline__ void s_body(int blk, char* smemraw,
    const float* __restrict__ hidden, const float* __restrict__ norms,
    double* __restrict__ rowsum, double* __restrict__ psum)
{
  SS* sm = (SS*)smemraw;
  const int b = blk >> 4;
  const int i0 = (blk & 15) * 64;
  const int tid = threadIdx.x, l = tid & 63, wv = tid >> 6;
  const int m = l & 15, q = l >> 4;
  const float* hb = hidden + (size_t)b*T_*H_;
  const float* nb = norms + (size_t)b*T_;

  for(int idx=tid; idx<64*32; idx+=256){
    const int r = idx>>5, k4 = (idx&31)*4;
    float4 v = *(const float4*)&hb[(size_t)(i0+r)*H_ + k4];
    const float inv = 1.f/nb[i0+r];
    const float f0=v.x*inv, f1=v.y*inv, f2=v.z*inv, f3=v.w*inv;
    const unsigned short h0=bf1(f0), h1=bf1(f1), h2=bf1(f2), h3=bf1(f3);
    uint2 phi; phi.x = (unsigned)h0 | ((unsigned)h1<<16); phi.y = (unsigned)h2 | ((unsigned)h3<<16);
    *(uint2*)&sm->Ahi[r*136 + k4] = phi;
    const unsigned short g0=bf1(f0-bf2f(h0)), g1=bf1(f1-bf2f(h1)), g2=bf1(f2-bf2f(h2)), g3=bf1(f3-bf2f(h3));
    uint2 plo; plo.x = (unsigned)g0 | ((unsigned)g1<<16); plo.y = (unsigned)g2 | ((unsigned)g3<<16);
    *(uint2*)&sm->Alo[r*136 + k4] = plo;
  }

  double rs[4]={0,0,0,0}, ps[4]={0,0,0,0};
  const int arow = (wv*16 + m)*136;

  for(int jt=0;jt<16;jt++){
    const int j0 = jt*64;
    __syncthreads();
    for(int idx=tid; idx<64*32; idx+=256){
      const int r = idx>>5, k4 = (idx&31)*4;
      float4 v = *(const float4*)&hb[(size_t)(j0+r)*H_ + k4];
      const float inv = 1.f/nb[j0+r];
      const float f0=v.x*inv, f1=v.y*inv, f2=v.z*inv, f3=v.w*inv;
      const unsigned short h0=bf1(f0), h1=bf1(f1), h2=bf1(f2), h3=bf1(f3);
      uint2 phi; phi.x = (unsigned)h0 | ((unsigned)h1<<16); phi.y = (unsigned)h2 | ((unsigned)h3<<16);
      *(uint2*)&sm->Bhi[r*136 + k4] = phi;
      const unsigned short g0=bf1(f0-bf2f(h0)), g1=bf1(f1-bf2f(h1)), g2=bf1(f2-bf2f(h2)), g3=bf1(f3-bf2f(h3));
      uint2 plo; plo.x = (unsigned)g0 | ((unsigned)g1<<16); plo.y = (unsigned)g2 | ((unsigned)g3<<16);
      *(uint2*)&sm->Blo[r*136 + k4] = plo;
    }
    __syncthreads();

    f32x4 acc[4];
    #pragma unroll
    for(int nt=0;nt<4;nt++) acc[nt] = (f32x4)(0.f);
    #pragma unroll
    for(int kc=0;kc<4;kc++){
      const bfrag Ah = *(const bfrag*)&sm->Ahi[arow + kc*32 + q*8];
      const bfrag Al = *(const bfrag*)&sm->Alo[arow + kc*32 + q*8];
      #pragma unroll
      for(int nt=0;nt<4;nt++){
        const int brow = (nt*16 + m)*136 + kc*32 + q*8;
        const bfrag Bh = *(const bfrag*)&sm->Bhi[brow];
        const bfrag Bl = *(const bfrag*)&sm->Blo[brow];
        acc[nt] = __builtin_amdgcn_mfma_f32_16x16x32_bf16(Ah, Bh, acc[nt], 0, 0, 0);
        acc[nt] = __builtin_amdgcn_mfma_f32_16x16x32_bf16(Al, Bh, acc[nt], 0, 0, 0);
        acc[nt] = __builtin_amdgcn_mfma_f32_16x16x32_bf16(Ah, Bl, acc[nt], 0, 0, 0);
      }
    }
    #pragma unroll
    for(int nt=0;nt<4;nt++){
      const int gj = j0 + nt*16 + m;
      #pragma unroll
      for(int r=0;r<4;r++){
        const int gi = i0 + wv*16 + q*4 + r;
        if(gi == gj) continue;
        const float sv = __expf(-5.5f*(1.f - acc[nt][r]));
        rs[r] += (double)sv;
        if(gj < gi) ps[r] += (double)sv;
      }
    }
  }
  __syncthreads();
  #pragma unroll
  for(int r=0;r<4;r++) sm->red[wv*16 + q*4 + r][m] = rs[r];
  __syncthreads();
  if(tid<64){ double v=0; for(int k=0;k<16;k++) v+=sm->red[tid][k]; rowsum[(size_t)b*T_ + i0 + tid]=v; }
  __syncthreads();
  #pragma unroll
  for(int r=0;r<4;r++) sm->red[wv*16 + q*4 + r][m] = ps[r];
  __syncthreads();
  if(tid<64){ double v=0; for(int k=0;k<16;k++) v+=sm->red[tid][k]; psum[(size_t)b*T_ + i0 + tid]=v; }
}

// ---- cluster: prefix+dist+argmax+corr
struct CS {
  double sr[256]; double sp[256]; double bd[256]; double totR;
  float c2[2][128]; int bidx[256]; int cut;
};
__device__ __forceinline__ void cluster_body(int b, char* smemraw,
    const double* __restrict__ rowsum, const double* __restrict__ psum,
    const float* __restrict__ hidden, float* __restrict__ corr, int* __restrict__ cuts)
{
  CS* sm = (CS*)smemraw;
  const int tid = threadIdx.x;
  const double* r = rowsum + (size_t)b*T_;
  const double* p = psum + (size_t)b*T_;
  double r4[4], p4[4];
  #pragma unroll
  for(int q=0;q<4;q++){ r4[q]=r[tid*4+q]; p4[q]=p[tid*4+q]; }
  sm->sr[tid]=r4[0]+r4[1]+r4[2]+r4[3];
  sm->sp[tid]=p4[0]+p4[1]+p4[2]+p4[3];
  __syncthreads();
  if(tid==0){
    double ar=0, ap=0;
    for(int i=0;i<256;i++){ double tr=sm->sr[i], tp=sm->sp[i]; sm->sr[i]=ar; sm->sp[i]=ap; ar+=tr; ap+=tp; }
    sm->totR = ar;
  }
  __syncthreads();
  double cr = sm->sr[tid], cp = sm->sp[tid];
  const double full = sm->totR;
  double best = -1e308; int bi = 1;
  #pragma unroll
  for(int q=0;q<4;q++){
    cr += r4[q]; cp += p4[q];
    const int i = 4*tid + q + 1;
    if(i < T_){
      const double TL = 2.0*cp;
      const double TRv = cr - TL;
      const double BR = full - TL - 2.0*TRv;
      const double di = (double)i, dn = (double)(T_-i);
      const double dist = TL/(di*di) + BR/(dn*dn) - (2.0*TRv)/(di*dn);
      if(dist > best){ best=dist; bi=i; }
    }
  }
  sm->bd[tid]=best; sm->bidx[tid]=bi;
  __syncthreads();
  if(tid==0){
    double bb=-1e308; int ii=1;
    for(int q=0;q<256;q++){ if(sm->bd[q]>bb){ bb=sm->bd[q]; ii=sm->bidx[q]; } }
    sm->cut=ii; cuts[b]=ii;
  }
  __syncthreads();
  const int cut = sm->cut;
  const int h = tid&127, half = tid>>7;
  float s=0.f;
  const float* hb = hidden + (size_t)b*T_*H_;
  #pragma unroll 4
  for(int t=half; t<cut; t+=2) s += hb[(size_t)t*H_ + h];
  sm->c2[half][h]=s;
  __syncthreads();
  if(tid<128) corr[b*H_+tid] = (sm->c2[0][tid]+sm->c2[1][tid])/(float)cut;
}

// ---- VAE head1 (256 threads; upper half idles)
__device__ __forceinline__ void head1_body(int b, char* smemraw,
    const float* __restrict__ corr, const float* __restrict__ hidden,
    const float* __restrict__ eps_z, const float* __restrict__ eps_cat,
    const float* __restrict__ mu_w, const float* __restrict__ mu_b,
    const float* __restrict__ std_w, const float* __restrict__ std_b,
    const float* __restrict__ muc_w, const float* __restrict__ muc_b,
    const float* __restrict__ stdc_w, const float* __restrict__ stdc_b,
    float* __restrict__ out_mu, float* __restrict__ out_std,
    float* __restrict__ out_muc, float* __restrict__ out_stdc, float* __restrict__ x1)
{
  struct H1 { float cs[128]; float xz[256]; };
  H1* sm = (H1*)smemraw;
  const int h = threadIdx.x;
  if(h<128){
    sm->cs[h]=corr[b*H_+h];
    sm->xz[h]=hidden[((size_t)b*T_ + (T_-1))*H_ + h];
  }
  __syncthreads();
  if(h<128){
    float m=mu_b[h], sdv=std_b[h];
    for(int k=0;k<H_;k++){ const float cv=sm->cs[k]; m+=cv*mu_w[k*H_+h]; sdv+=cv*std_w[k*H_+h]; }
    const float stdv = softplus_(sdv);
    out_mu[b*H_+h]=m; out_std[b*H_+h]=stdv;
    sm->xz[128+h] = m + stdv*eps_z[b*H_+h];
  }
  __syncthreads();
  if(h<128){
    float mc=muc_b[h], sc=stdc_b[h];
    for(int k=0;k<256;k++){ const float v=sm->xz[k]; mc+=v*muc_w[k*H_+h]; sc+=v*stdc_w[k*H_+h]; }
    const float stdc = softplus_(sc);
    out_muc[b*H_+h]=mc; out_stdc[b*H_+h]=stdc;
    x1[b*H_+h]=mc + stdc*eps_cat[b*H_+h];
  }
}

// ---- causal conv via bf16 MFMA + fused BN partials + optional inline SE scale
// (R10 shape: NT=4 co-groups via `by`; staging applies SE scale only — no gelu)
struct ConvS {
  float sescale[256];
  float seh[16];
  unsigned short xs[72*40];   // bf16 staging; reused as float part[]/ms[]
};
__device__ __forceinline__ void conv_body(int bx, int by, int bz, char* smemraw,
    const float* __restrict__ in, const unsigned short* __restrict__ wp,
    const float* __restrict__ bias,
    const float* __restrict__ se_in, const float* __restrict__ se_w1,
    const float* __restrict__ se_w2, int seR,
    float* __restrict__ y, float* __restrict__ bnacc, int Cin, int Cout, int Kw)
{
  ConvS* sm = (ConvS*)smemraw;
  unsigned short* xs = sm->xs;
  const int b = bz, t0 = bx*64, co0 = by*64;
  const int tid = threadIdx.x, l = tid&63, wv = tid>>6;
  const int q = l>>4, m = l&15;
  const int TW = 64 + Kw - 1;
  const int abase = (wv*16 + m)*40 + q*8;
  const int boff = (m*4 + q)*8;
  const bool use_se = (se_in != nullptr);

  if(use_se){
    float* ms = (float*)xs;   // temp, overwritten by staging later
    if(tid<Cin) ms[tid] = se_in[b*Cin+tid] * (1.f/(float)T_);
    __syncthreads();
    if(tid<seR){ float s=0.f; for(int k=0;k<Cin;k++) s += ms[k]*se_w1[k*seR+tid]; sm->seh[tid]=fmaxf(s,0.f); }
    __syncthreads();
    if(tid<Cin){ float s=0.f; for(int k=0;k<seR;k++) s += sm->seh[k]*se_w2[k*Cin+tid]; sm->sescale[tid]=sig_(s); }
  }

  f32x4 acc[4];
  #pragma unroll
  for(int nt=0;nt<4;nt++) acc[nt] = (f32x4)(0.f);

  const int nchunks = Cin >> 5;
  for(int cc=0; cc<nchunks; cc++){
    __syncthreads();
    for(int idx=tid; idx<TW*8; idx+=256){
      const int r = idx>>3, c4 = (idx&7)*4;
      const int tg = t0 - (Kw-1) + r;
      uint2 pk = make_uint2(0u, 0u);
      if(tg >= 0){
        float4 v = *(const float4*)&in[((size_t)b*T_ + tg)*Cin + cc*32 + c4];
        if(use_se){
          const float4 s4 = *(const float4*)&sm->sescale[cc*32 + c4];
          v.x*=s4.x; v.y*=s4.y; v.z*=s4.z; v.w*=s4.w;
        }
        pk.x = bfpack(v.x, v.y); pk.y = bfpack(v.z, v.w);
      }
      *(uint2*)&xs[r*40 + c4] = pk;
    }
    __syncthreads();
    for(int kw=0; kw<Kw; kw++){
      const bfrag Af = *(const bfrag*)&xs[abase + kw*40];
      #pragma unroll
      for(int nt=0; nt<4; nt++){
        const unsigned short* wpp = wp + ((size_t)((cc*Kw + kw)*(Cout>>4) + (by*4 + nt)))*512 + boff;
        const bfrag Bf = *(const bfrag*)wpp;
        acc[nt] = __builtin_amdgcn_mfma_f32_16x16x32_bf16(Af, Bf, acc[nt], 0, 0, 0);
      }
    }
  }
  __syncthreads();
  float* part = (float*)xs;   // [4 wv][64 co][2]
  const int t_base = t0 + wv*16 + q*4;
  #pragma unroll
  for(int nt=0; nt<4; nt++){
    const int co = co0 + nt*16 + m;
    const float bv = bias[co];
    float s1 = 0.f, s2 = 0.f;
    #pragma unroll
    for(int r=0;r<4;r++){
      const float v = acc[nt][r] + bv;
      y[((size_t)b*T_ + t_base + r)*Cout + co] = v;
      s1 += v; s2 += v*v;
    }
    s1 += __shfl_xor(s1, 16); s1 += __shfl_xor(s1, 32);
    s2 += __shfl_xor(s2, 16); s2 += __shfl_xor(s2, 32);
    if(q==0){ part[(wv*64 + nt*16 + m)*2+0] = s1; part[(wv*64 + nt*16 + m)*2+1] = s2; }
  }
  __syncthreads();
  if(tid < 64){
    float a1=0.f, a2=0.f;
    #pragma unroll
    for(int w2i=0; w2i<4; w2i++){ a1 += part[(w2i*64+tid)*2+0]; a2 += part[(w2i*64+tid)*2+1]; }
    atomicAdd(&bnacc[co0 + tid], a1);
    atomicAdd(&bnacc[Cout + co0 + tid], a2);
  }
}

// ---- BN + gelu (writes activated y) + per-(b,c) t-sum accum
__device__ __forceinline__ void bn_act_body(int b, int chunk, char* smemraw,
    float* __restrict__ y, const float* __restrict__ bnacc,
    const float* __restrict__ gw, const float* __restrict__ bw,
    float* __restrict__ mean_acc, int C)
{
  const int t0 = chunk*128, tid = threadIdx.x;
  const int c = tid & (C-1), part = tid / C, np = 256 / C;
  const float cnt = (float)(B_*T_);
  const float mm = bnacc[c]/cnt;
  const float var = bnacc[C+c]/cnt - mm*mm;
  const float sc = gw[c]/sqrtf(var+1e-3f);
  const float sh = bw[c] - mm*sc;
  float s = 0.f;
  for(int t=t0+part; t<t0+128; t+=np){
    const size_t off = ((size_t)b*T_ + t)*C + c;
    float v = y[off];
    v = gelu_(v*sc + sh);
    y[off] = v;
    s += v;
  }
  float* rs = (float*)smemraw;
  if(np > 1){
    rs[tid]=s;
    __syncthreads();
    if(part==0) s += rs[tid+C];
  }
  if(part==0) atomicAdd(&mean_acc[b*C+c], s);
}

// ================================================================ kernels

__global__ __launch_bounds__(256) void mega0_kernel(
    const float* c1w, const float* c2w, const float* c3w,
    unsigned short* wp1, unsigned short* wp2, unsigned short* wp3,
    const float* x, const float* kw1, const float* kb1, float* axT)
{
  __shared__ __align__(16) char sm[16*68*4 + 64*16*4];
  const int bid = blockIdx.x;
  if(bid < 1280) prepack_body(bid, c1w, c2w, c3w, wp1, wp2, wp3);
  else ax_body(bid-1280, sm, x, kw1, kb1, axT);
}

// D1: lstm (32 blocks) + conv1 workers (224 blocks, strided over 1024 tiles).
// Exactly 256 blocks -> 1 block/CU: conv1 never co-resides with lstm.
__global__ __launch_bounds__(256, 1) void megaL_kernel(
    const float* axT, const float* kw1, const float* kw2, const float* kb2, float* hidden,
    const float* x, const unsigned short* wp1, const float* c1b, float* y1, float* bn1)
{
  __shared__ __align__(16) char sm[sizeof(ConvS)];
  const int bid = blockIdx.x;
  if(bid < 32){
    lstm_body(bid, sm, axT, kw1, kw2, kb2, hidden);
  } else {
    const int w = bid - 32;
    for(int t=w; t<1024; t+=224)
      conv_body(t&15, (t>>4)&1, t>>5, sm, x, wp1, c1b,
                nullptr, nullptr, nullptr, 0, y1, bn1, F_, C1_, 8);
  }
}

// D2: norm (4096) + bn_act1 (256)
__global__ __launch_bounds__(256) void megaA_kernel(
    const float* hidden, float* norms,
    float* y1, const float* bn1, const float* g1w, const float* b1w, float* se1_in)
{
  __shared__ __align__(16) char sm[1024];
  const int bid = blockIdx.x;
  if(bid < 4096) norm_body(bid, hidden, norms);
  else { const int cb = bid-4096; bn_act_body(cb>>3, cb&7, sm, y1, bn1, g1w, b1w, se1_in, C1_); }
}

// D3: s (512)
__global__ __launch_bounds__(256) void s_kernel(
    const float* hidden, const float* norms, double* rowsum, double* psum)
{
  __shared__ __align__(16) char sm[sizeof(SS)];
  s_body(blockIdx.x, sm, hidden, norms, rowsum, psum);
}

// D4: cluster (32) + conv2 w/ inline SE1 (2048)
__global__ __launch_bounds__(256) void megaC_kernel(
    const double* rowsum, const double* psum, const float* hidden, float* corr, int* cuts,
    const float* y1, const unsigned short* wp2, const float* c2b,
    const float* se1_in, const float* s1w1, const float* s1w2,
    float* y2, float* bn2)
{
  __shared__ __align__(16) char sm[sizeof(CS) > sizeof(ConvS) ? sizeof(CS) : sizeof(ConvS)];
  const int bid = blockIdx.x;
  if(bid < 32) cluster_body(bid, sm, rowsum, psum, hidden, corr, cuts);
  else {
    const int cb = bid - 32;
    conv_body(cb&15, (cb>>4)&3, cb>>6, sm, y1, wp2, c2b,
              se1_in, s1w1, s1w2, C1_/16, y2, bn2, C1_, C2_, 5);
  }
}

// D5: head1 (32) + bn_act2 (256)
__global__ __launch_bounds__(256) void megaD_kernel(
    const float* corr, const float* hidden, const float* eps_z, const float* eps_cat,
    const float* mu_w, const float* mu_b, const float* std_w, const float* std_b,
    const float* muc_w, const float* muc_b, const float* stdc_w, const float* stdc_b,
    float* out_mu, float* out_std, float* out_muc, float* out_stdc, float* x1,
    float* y2, const float* bn2, const float* g2w, const float* b2w, float* se2_in)
{
  __shared__ __align__(16) char sm[1536];
  const int bid = blockIdx.x;
  if(bid < 32) head1_body(bid, sm, corr, hidden, eps_z, eps_cat, mu_w, mu_b, std_w, std_b,
                          muc_w, muc_b, stdc_w, stdc_b, out_mu, out_std, out_muc, out_stdc, x1);
  else { const int cb = bid-32; bn_act_body(cb>>3, cb&7, sm, y2, bn2, g2w, b2w, se2_in, C2_); }
}

// D6: conv3 w/ inline SE2 (1024)
__global__ __launch_bounds__(256) void conv3_kernel(
    const float* y2, const unsigned short* wp3, const float* c3b,
    const float* se2_in, const float* s2w1, const float* s2w2,
    float* y3, float* bn3)
{
  __shared__ __align__(16) char sm[sizeof(ConvS)];
  const int bid = blockIdx.x;
  conv_body(bid&15, (bid>>4)&1, bid>>5, sm, y2, wp3, c3b,
            se2_in, s2w1, s2w2, C2_/16, y3, bn3, C2_, C3_, 3);
}

// D7: bn3+gelu+t-mean fused with final fc + log_softmax
__global__ __launch_bounds__(256) void head2_kernel(
    const float* __restrict__ y3, const float* __restrict__ bn3,
    const float* __restrict__ g3w, const float* __restrict__ b3w,
    const float* __restrict__ x1,
    const float* __restrict__ fcw, const float* __restrict__ fcb, float* __restrict__ outls)
{
  __shared__ float red[256];
  __shared__ float xa[256];
  __shared__ float lg[NC_];
  const int b = blockIdx.x, tid = threadIdx.x;
  const int c = tid & 127, part = tid >> 7;
  const float cnt = (float)(B_*T_);
  const float mm = bn3[c]/cnt;
  const float var = bn3[128+c]/cnt - mm*mm;
  const float sc = g3w[c]/sqrtf(var+1e-3f);
  const float sh = b3w[c] - mm*sc;
  float s = 0.f;
  for(int t=part; t<T_; t+=2){
    const float v = y3[((size_t)b*T_ + t)*C3_ + c];
    s += gelu_(v*sc + sh);
  }
  red[tid] = s;
  __syncthreads();
  if(part==0) xa[128+c] = (red[c] + red[128+c]) * (1.f/(float)T_);
  else xa[c] = x1[b*128+c];
  __syncthreads();
  if(tid<NC_){
    float sa = fcb[tid];
    for(int k=0;k<256;k++) sa += xa[k]*fcw[k*NC_+tid];
    lg[tid]=sa;
  }
  __syncthreads();
  if(tid==0){
    float mx=lg[0];
    for(int q=1;q<NC_;q++) mx=fmaxf(mx,lg[q]);
    float se=0;
    for(int q=0;q<NC_;q++) se += __expf(lg[q]-mx);
    const float lse = logf(se)+mx;
    for(int q=0;q<NC_;q++) outls[b*NC_+q] = lg[q]-lse;
  }
}

// ================================================================ launch
extern "C" void kernel_launch(void* const* d_in, const int* in_sizes, int n_in,
                              void* d_out, int out_size, void* d_ws, size_t ws_size,
                              hipStream_t stream) {
  (void)in_sizes; (void)n_in; (void)out_size; (void)ws_size;
  const float* x        = (const float*)d_in[0];
  const float* eps_z    = (const float*)d_in[1];
  const float* eps_cat  = (const float*)d_in[2];
  const float* kan_w1   = (const float*)d_in[3];
  const float* kan_b1   = (const float*)d_in[4];
  const float* kan_w2   = (const float*)d_in[5];
  const float* kan_b2   = (const float*)d_in[6];
  const float* conv1_w  = (const float*)d_in[7];
  const float* conv1_b  = (const float*)d_in[8];
  const float* conv2_w  = (const float*)d_in[9];
  const float* conv2_b  = (const float*)d_in[10];
  const float* conv3_w  = (const float*)d_in[11];
  const float* conv3_b  = (const float*)d_in[12];
  const float* bn1_g    = (const float*)d_in[13];
  const float* bn1_b    = (const float*)d_in[14];
  const float* bn2_g    = (const float*)d_in[15];
  const float* bn2_b    = (const float*)d_in[16];
  const float* bn3_g    = (const float*)d_in[17];
  const float* bn3_b    = (const float*)d_in[18];
  const float* se1_w1   = (const float*)d_in[19];
  const float* se1_w2   = (const float*)d_in[20];
  const float* se2_w1   = (const float*)d_in[21];
  const float* se2_w2   = (const float*)d_in[22];
  const float* fc_mu_w  = (const float*)d_in[23];
  const float* fc_mu_b  = (const float*)d_in[24];
  const float* fc_std_w = (const float*)d_in[25];
  const float* fc_std_b = (const float*)d_in[26];
  const float* fc_muc_w = (const float*)d_in[27];
  const float* fc_muc_b = (const float*)d_in[28];
  const float* fc_stdc_w= (const float*)d_in[29];
  const float* fc_stdc_b= (const float*)d_in[30];
  const float* fc_w     = (const float*)d_in[31];
  const float* fc_b     = (const float*)d_in[32];

  float* out = (float*)d_out;
  float* out_ls   = out;
  float* out_mu   = out + 320;
  float* out_std  = out + 320 + 4096;
  float* out_muc  = out + 320 + 2*4096;
  float* out_stdc = out + 320 + 3*4096;

  float* ws = (float*)d_ws;
  const size_t SZ_HID = (size_t)B_*T_*H_;
  const size_t SZ_Y1  = (size_t)B_*T_*C1_;
  const size_t SZ_Y2  = (size_t)B_*T_*C2_;
  float*  hidden = ws;                      // [b][t][H] — never aliased
  float*  y1     = hidden + SZ_HID;         // conv1 out (activated in-place); reused as y3 after conv2
  float*  y2     = y1 + SZ_Y1;
  float*  norms  = y2 + SZ_Y2;
  double* rowsum = (double*)(norms + (size_t)B_*T_);
  double* psum   = rowsum + (size_t)B_*T_;
  float*  corr   = (float*)(psum + (size_t)B_*T_);
  float*  x1     = corr + (size_t)B_*H_;
  float*  bnbuf  = x1 + (size_t)B_*H_;      // zeroed region starts here
  float*  bn1    = bnbuf;
  float*  bn2    = bnbuf + 2*C1_;
  float*  bn3    = bnbuf + 2*C1_ + 2*C2_;
  float*  se1_in = bnbuf + 1024;
  float*  se2_in = se1_in + (size_t)B_*C1_;
  int*    cuts   = (int*)(se2_in + (size_t)B_*C2_);
  float*  axbuf  = (float*)(cuts + B_);     // axT: B*16*T
  unsigned short* wp1 = (unsigned short*)(axbuf + (size_t)B_*16*T_);
  unsigned short* wp2 = wp1 + (size_t)C1_*F_*8;
  unsigned short* wp3 = wp2 + (size_t)C2_*C1_*5;
  float*  y3     = y1;   // y1 dead after D4 (conv2); conv3 (D6) reuses it

  // zero bn accumulators + se t-sum accumulators
  hipMemsetAsync(bnbuf, 0, (size_t)(1024 + B_*C1_ + B_*C2_)*sizeof(float), stream);

  // D0: prepack (1280) + ax (2048)
  mega0_kernel<<<3328, 256, 0, stream>>>(conv1_w, conv2_w, conv3_w, wp1, wp2, wp3,
                                         x, kan_w1, kan_b1, axbuf);
  // D1: lstm + conv1 workers (exactly 256 blocks -> CU isolation)
  megaL_kernel<<<256, 256, 0, stream>>>(axbuf, kan_w1, kan_w2, kan_b2, hidden,
                                        x, wp1, conv1_b, y1, bn1);
  // D2: norm + bn_act1 (writes activated y1 + SE sums)
  megaA_kernel<<<4096 + 256, 256, 0, stream>>>(hidden, norms, y1, bn1, bn1_g, bn1_b, se1_in);
  // D3: s
  s_kernel<<<512, 256, 0, stream>>>(hidden, norms, rowsum, psum);
  // D4: cluster + conv2 (inline SE1 scale)
  megaC_kernel<<<32 + 2048, 256, 0, stream>>>(rowsum, psum, hidden, corr, cuts,
                                              y1, wp2, conv2_b, se1_in, se1_w1, se1_w2, y2, bn2);
  // D5: head1 + bn_act2 (writes activated y2 + SE sums)
  megaD_kernel<<<32 + 256, 256, 0, stream>>>(corr, hidden, eps_z, eps_cat,
      fc_mu_w, fc_mu_b, fc_std_w, fc_std_b, fc_muc_w, fc_muc_b, fc_stdc_w, fc_stdc_b,
      out_mu, out_std, out_muc, out_stdc, x1,
      y2, bn2, bn2_g, bn2_b, se2_in);
  // D6: conv3 (inline SE2 scale)
  conv3_kernel<<<1024, 256, 0, stream>>>(y2, wp3, conv3_b, se2_in, se2_w1, se2_w2, y3, bn3);
  // D7: bn3+gelu+mean fused with final head
  head2_kernel<<<B_, 256, 0, stream>>>(y3, bn3, bn3_g, bn3_b, x1, fc_w, fc_b, out_ls);
}

// Round 14
// 900.774 us; speedup vs baseline: 1.3010x; 1.3010x over previous
//
#include <hip/hip_runtime.h>
#include <math.h>

#define B_ 32
#define T_ 1024
#define F_ 64
#define H_ 128
#define D_ 192
#define KH_ 16
#define C1_ 128
#define C2_ 256
#define C3_ 128
#define NC_ 10

typedef float v2f __attribute__((ext_vector_type(2)));
typedef float f32x4 __attribute__((ext_vector_type(4)));
typedef __bf16 bfrag __attribute__((ext_vector_type(8)));

__device__ __forceinline__ float sig_(float x){ return 1.f/(1.f+__expf(-x)); }
__device__ __forceinline__ float tanh_(float x){ return 1.f - 2.f/(__expf(2.f*x)+1.f); }
__device__ __forceinline__ float gelu_(float x){ return 0.5f*x*(1.f+erff(x*0.70710678118654752f)); }
__device__ __forceinline__ float softplus_(float x){ return fmaxf(x,0.f) + log1pf(__expf(-fabsf(x))); }

__device__ __forceinline__ unsigned bfpack(float a, float b){
  unsigned ua = __float_as_uint(a), ub = __float_as_uint(b);
  ua = ua + 0x7FFFu + ((ua>>16)&1u);
  ub = ub + 0x7FFFu + ((ub>>16)&1u);
  return (ua>>16) | (ub & 0xFFFF0000u);
}
__device__ __forceinline__ unsigned short bf1(float a){
  unsigned ua = __float_as_uint(a);
  ua = ua + 0x7FFFu + ((ua>>16)&1u);
  return (unsigned short)(ua>>16);
}
__device__ __forceinline__ float bf2f(unsigned short h){
  return __uint_as_float(((unsigned)h)<<16);
}

#define QPERM_XOR1(x) __int_as_float(__builtin_amdgcn_mov_dpp(__float_as_int(x), 0xB1, 0xF, 0xF, true))
#define QPERM_XOR2(x) __int_as_float(__builtin_amdgcn_mov_dpp(__float_as_int(x), 0x4E, 0xF, 0xF, true))

#define LDS_BARRIER() asm volatile("s_waitcnt lgkmcnt(0)\n\ts_barrier" ::: "memory")

// ================================================================ bodies

// ---- ax precompute (transposed out: axT[b][j][t])
__device__ __forceinline__ void ax_body(int blk, char* smemraw,
    const float* __restrict__ x, const float* __restrict__ w1, const float* __restrict__ b1,
    float* __restrict__ axT)
{
  struct AxS { float xs[16][68]; float w1s[64][16]; };
  AxS* sm = (AxS*)smemraw;
  const int bt0 = blk*16;
  const int tid = threadIdx.x;
  for(int i=tid;i<64*16;i+=256){ sm->w1s[i>>4][i&15] = w1[i]; }
  for(int i=tid;i<16*64;i+=256){ const int r=i>>6, d=i&63; sm->xs[r][d] = x[(size_t)(bt0+r)*64 + d]; }
  __syncthreads();
  const int r = tid>>4, j = tid&15;
  float s = b1[j];
  #pragma unroll
  for(int d=0; d<64; d++) s += sm->xs[r][d]*sm->w1s[d][j];
  const int bt = bt0 + r;
  axT[((size_t)(bt>>10)*16 + j)*1024 + (bt&1023)] = s;
}

// ---- weight prepack (bf16 MFMA B-fragment blocks, all 3 convs)
__device__ __forceinline__ void prepack_body(int blk,
    const float* __restrict__ w1s, const float* __restrict__ w2s, const float* __restrict__ w3s,
    unsigned short* __restrict__ wp1, unsigned short* __restrict__ wp2, unsigned short* __restrict__ wp3)
{
  int e = blk*256 + threadIdx.x;
  if(e >= 65536+163840+98304) return;
  const float* w; unsigned short* wp; int Cout, Cin, Kw;
  if(e < 65536){ w=w1s; wp=wp1; Cout=C1_; Cin=F_;  Kw=8; }
  else if(e < 65536+163840){ e-=65536; w=w2s; wp=wp2; Cout=C2_; Cin=C1_; Kw=5; }
  else { e-=229376; w=w3s; wp=wp3; Cout=C3_; Cin=C2_; Kw=3; }
  const int co = e/(Cin*Kw);
  const int rem = e - co*(Cin*Kw);
  const int ci = rem/Kw, kw = rem - ci*Kw;
  const int off = (((ci>>5)*Kw + kw)*(Cout>>4) + (co>>4))*512 + ((co&15)*4 + ((ci>>3)&3))*8 + (ci&7);
  wp[off] = bf1(w[e]);
}

// ---- row norms + write normalized rows as bf16 hi/lo (hoisted out of s_kernel)
__device__ __forceinline__ void norm_body(int blk,
    const float* __restrict__ hidden,
    unsigned short* __restrict__ hnhi, unsigned short* __restrict__ hnlo)
{
  const int row = blk*8 + (threadIdx.x>>5);
  const int l = threadIdx.x&31;
  const float* hr = hidden + (size_t)row*H_;
  float s = 0.f;
  for(int k=l;k<H_;k+=32){ float v=hr[k]; s+=v*v; }
  #pragma unroll
  for(int m=16;m>=1;m>>=1) s += __shfl_xor(s, m, 64);
  const float inv = 1.f/fmaxf(sqrtf(s), 1e-8f);
  const float4 v = *(const float4*)&hr[l*4];
  const float f0=v.x*inv, f1=v.y*inv, f2=v.z*inv, f3=v.w*inv;
  const unsigned short h0=bf1(f0), h1=bf1(f1), h2=bf1(f2), h3=bf1(f3);
  uint2 phi; phi.x = (unsigned)h0 | ((unsigned)h1<<16); phi.y = (unsigned)h2 | ((unsigned)h3<<16);
  *(uint2*)&hnhi[(size_t)row*H_ + l*4] = phi;
  const unsigned short g0=bf1(f0-bf2f(h0)), g1=bf1(f1-bf2f(h1)), g2=bf1(f2-bf2f(h2)), g3=bf1(f3-bf2f(h3));
  uint2 plo; plo.x = (unsigned)g0 | ((unsigned)g1<<16); plo.y = (unsigned)g2 | ((unsigned)g3<<16);
  *(uint2*)&hnlo[(size_t)row*H_ + l*4] = plo;
}

// ---- S rowsums via bf16 MFMA (hi/lo split Gram, pre-converted inputs)
struct SS {
  unsigned short Ahi[64*136];
  unsigned short Alo[64*136];
  unsigned short Bhi[64*136];
  unsigned short Blo[64*136];
  double red[64][17];
};
__device__ __forceinline__ void s_body(int blk, char* smemraw,
    const unsigned short* __restrict__ hnhi, const unsigned short* __restrict__ hnlo,
    double* __restrict__ rowsum, double* __restrict__ psum)
{
  SS* sm = (SS*)smemraw;
  const int b = blk >> 4;
  const int i0 = (blk & 15) * 64;
  const int tid = threadIdx.x, l = tid & 63, wv = tid >> 6;
  const int m = l & 15, q = l >> 4;

  // stage A rows (pure copies, 16B)
  {
    const uint4* ghi = (const uint4*)(hnhi + ((size_t)b*T_ + i0)*H_);
    const uint4* glo = (const uint4*)(hnlo + ((size_t)b*T_ + i0)*H_);
    for(int idx=tid; idx<64*16; idx+=256){
      const int r = idx>>4, c8 = idx&15;
      *(uint4*)&sm->Ahi[r*136 + c8*8] = ghi[r*16 + c8];
      *(uint4*)&sm->Alo[r*136 + c8*8] = glo[r*16 + c8];
    }
  }

  double rs[4]={0,0,0,0}, ps[4]={0,0,0,0};
  const int arow = (wv*16 + m)*136;

  for(int jt=0;jt<16;jt++){
    const int j0 = jt*64;
    __syncthreads();
    {
      const uint4* ghi = (const uint4*)(hnhi + ((size_t)b*T_ + j0)*H_);
      const uint4* glo = (const uint4*)(hnlo + ((size_t)b*T_ + j0)*H_);
      for(int idx=tid; idx<64*16; idx+=256){
        const int r = idx>>4, c8 = idx&15;
        *(uint4*)&sm->Bhi[r*136 + c8*8] = ghi[r*16 + c8];
        *(uint4*)&sm->Blo[r*136 + c8*8] = glo[r*16 + c8];
      }
    }
    __syncthreads();

    f32x4 acc[4];
    #pragma unroll
    for(int nt=0;nt<4;nt++) acc[nt] = (f32x4)(0.f);
    #pragma unroll
    for(int kc=0;kc<4;kc++){
      const bfrag Ah = *(const bfrag*)&sm->Ahi[arow + kc*32 + q*8];
      const bfrag Al = *(const bfrag*)&sm->Alo[arow + kc*32 + q*8];
      #pragma unroll
      for(int nt=0;nt<4;nt++){
        const int brow = (nt*16 + m)*136 + kc*32 + q*8;
        const bfrag Bh = *(const bfrag*)&sm->Bhi[brow];
        const bfrag Bl = *(const bfrag*)&sm->Blo[brow];
        acc[nt] = __builtin_amdgcn_mfma_f32_16x16x32_bf16(Ah, Bh, acc[nt], 0, 0, 0);
        acc[nt] = __builtin_amdgcn_mfma_f32_16x16x32_bf16(Al, Bh, acc[nt], 0, 0, 0);
        acc[nt] = __builtin_amdgcn_mfma_f32_16x16x32_bf16(Ah, Bl, acc[nt], 0, 0, 0);
      }
    }
    #pragma unroll
    for(int nt=0;nt<4;nt++){
      const int gj = j0 + nt*16 + m;
      #pragma unroll
      for(int r=0;r<4;r++){
        const int gi = i0 + wv*16 + q*4 + r;
        if(gi == gj) continue;
        const float sv = __expf(-5.5f*(1.f - acc[nt][r]));
        rs[r] += (double)sv;
        if(gj < gi) ps[r] += (double)sv;
      }
    }
  }
  __syncthreads();
  #pragma unroll
  for(int r=0;r<4;r++) sm->red[wv*16 + q*4 + r][m] = rs[r];
  __syncthreads();
  if(tid<64){ double v=0; for(int k=0;k<16;k++) v+=sm->red[tid][k]; rowsum[(size_t)b*T_ + i0 + tid]=v; }
  __syncthreads();
  #pragma unroll
  for(int r=0;r<4;r++) sm->red[wv*16 + q*4 + r][m] = ps[r];
  __syncthreads();
  if(tid<64){ double v=0; for(int k=0;k<16;k++) v+=sm->red[tid][k]; psum[(size_t)b*T_ + i0 + tid]=v; }
}

// ---- cluster: prefix+dist+argmax+corr
struct CS {
  double sr[256]; double sp[256]; double bd[256]; double totR;
  float c2[2][128]; int bidx[256]; int cut;
};
__device__ __forceinline__ void cluster_body(int b, char* smemraw,
    const double* __restrict__ rowsum, const double* __restrict__ psum,
    const float* __restrict__ hidden, float* __restrict__ corr, int* __restrict__ cuts)
{
  CS* sm = (CS*)smemraw;
  const int tid = threadIdx.x;
  const double* r = rowsum + (size_t)b*T_;
  const double* p = psum + (size_t)b*T_;
  double r4[4], p4[4];
  #pragma unroll
  for(int q=0;q<4;q++){ r4[q]=r[tid*4+q]; p4[q]=p[tid*4+q]; }
  sm->sr[tid]=r4[0]+r4[1]+r4[2]+r4[3];
  sm->sp[tid]=p4[0]+p4[1]+p4[2]+p4[3];
  __syncthreads();
  if(tid==0){
    double ar=0, ap=0;
    for(int i=0;i<256;i++){ double tr=sm->sr[i], tp=sm->sp[i]; sm->sr[i]=ar; sm->sp[i]=ap; ar+=tr; ap+=tp; }
    sm->totR = ar;
  }
  __syncthreads();
  double cr = sm->sr[tid], cp = sm->sp[tid];
  const double full = sm->totR;
  double best = -1e308; int bi = 1;
  #pragma unroll
  for(int q=0;q<4;q++){
    cr += r4[q]; cp += p4[q];
    const int i = 4*tid + q + 1;
    if(i < T_){
      const double TL = 2.0*cp;
      const double TRv = cr - TL;
      const double BR = full - TL - 2.0*TRv;
      const double di = (double)i, dn = (double)(T_-i);
      const double dist = TL/(di*di) + BR/(dn*dn) - (2.0*TRv)/(di*dn);
      if(dist > best){ best=dist; bi=i; }
    }
  }
  sm->bd[tid]=best; sm->bidx[tid]=bi;
  __syncthreads();
  if(tid==0){
    double bb=-1e308; int ii=1;
    for(int q=0;q<256;q++){ if(sm->bd[q]>bb){ bb=sm->bd[q]; ii=sm->bidx[q]; } }
    sm->cut=ii; cuts[b]=ii;
  }
  __syncthreads();
  const int cut = sm->cut;
  const int h = tid&127, half = tid>>7;
  float s=0.f;
  const float* hb = hidden + (size_t)b*T_*H_;
  #pragma unroll 4
  for(int t=half; t<cut; t+=2) s += hb[(size_t)t*H_ + h];
  sm->c2[half][h]=s;
  __syncthreads();
  if(tid<128) corr[b*H_+tid] = (sm->c2[0][tid]+sm->c2[1][tid])/(float)cut;
}

// ---- VAE head1 (256 threads; upper half idles)
__device__ __forceinline__ void head1_body(int b, char* smemraw,
    const float* __restrict__ corr, const float* __restrict__ hidden,
    const float* __restrict__ eps_z, const float* __restrict__ eps_cat,
    const float* __restrict__ mu_w, const float* __restrict__ mu_b,
    const float* __restrict__ std_w, const float* __restrict__ std_b,
    const float* __restrict__ muc_w, const float* __restrict__ muc_b,
    const float* __restrict__ stdc_w, const float* __restrict__ stdc_b,
    float* __restrict__ out_mu, float* __restrict__ out_std,
    float* __restrict__ out_muc, float* __restrict__ out_stdc, float* __restrict__ x1)
{
  struct H1 { float cs[128]; float xz[256]; };
  H1* sm = (H1*)smemraw;
  const int h = threadIdx.x;
  if(h<128){
    sm->cs[h]=corr[b*H_+h];
    sm->xz[h]=hidden[((size_t)b*T_ + (T_-1))*H_ + h];
  }
  __syncthreads();
  if(h<128){
    float m=mu_b[h], sdv=std_b[h];
    for(int k=0;k<H_;k++){ const float cv=sm->cs[k]; m+=cv*mu_w[k*H_+h]; sdv+=cv*std_w[k*H_+h]; }
    const float stdv = softplus_(sdv);
    out_mu[b*H_+h]=m; out_std[b*H_+h]=stdv;
    sm->xz[128+h] = m + stdv*eps_z[b*H_+h];
  }
  __syncthreads();
  if(h<128){
    float mc=muc_b[h], sc=stdc_b[h];
    for(int k=0;k<256;k++){ const float v=sm->xz[k]; mc+=v*muc_w[k*H_+h]; sc+=v*stdc_w[k*H_+h]; }
    const float stdc = softplus_(sc);
    out_muc[b*H_+h]=mc; out_stdc[b*H_+h]=stdc;
    x1[b*H_+h]=mc + stdc*eps_cat[b*H_+h];
  }
}

// ---- causal conv via bf16 MFMA + fused BN partials + optional inline SE scale
struct ConvS {
  float sescale[256];
  float seh[16];
  unsigned short xs[72*40];   // bf16 staging; reused as float part[]/ms[]
};
__device__ __forceinline__ void conv_body(int bx, int by, int bz, char* smemraw,
    const float* __restrict__ in, const unsigned short* __restrict__ wp,
    const float* __restrict__ bias,
    const float* __restrict__ se_in, const float* __restrict__ se_w1,
    const float* __restrict__ se_w2, int seR,
    float* __restrict__ y, float* __restrict__ bnacc, int Cin, int Cout, int Kw)
{
  ConvS* sm = (ConvS*)smemraw;
  unsigned short* xs = sm->xs;
  const int b = bz, t0 = bx*64, co0 = by*64;
  const int tid = threadIdx.x, l = tid&63, wv = tid>>6;
  const int q = l>>4, m = l&15;
  const int TW = 64 + Kw - 1;
  const int abase = (wv*16 + m)*40 + q*8;
  const int boff = (m*4 + q)*8;
  const bool use_se = (se_in != nullptr);

  if(use_se){
    float* ms = (float*)xs;   // temp, overwritten by staging later
    if(tid<Cin) ms[tid] = se_in[b*Cin+tid] * (1.f/(float)T_);
    __syncthreads();
    if(tid<seR){ float s=0.f; for(int k=0;k<Cin;k++) s += ms[k]*se_w1[k*seR+tid]; sm->seh[tid]=fmaxf(s,0.f); }
    __syncthreads();
    if(tid<Cin){ float s=0.f; for(int k=0;k<seR;k++) s += sm->seh[k]*se_w2[k*Cin+tid]; sm->sescale[tid]=sig_(s); }
  }

  f32x4 acc[4];
  #pragma unroll
  for(int nt=0;nt<4;nt++) acc[nt] = (f32x4)(0.f);

  const int nchunks = Cin >> 5;
  for(int cc=0; cc<nchunks; cc++){
    __syncthreads();
    for(int idx=tid; idx<TW*8; idx+=256){
      const int r = idx>>3, c4 = (idx&7)*4;
      const int tg = t0 - (Kw-1) + r;
      uint2 pk = make_uint2(0u, 0u);
      if(tg >= 0){
        float4 v = *(const float4*)&in[((size_t)b*T_ + tg)*Cin + cc*32 + c4];
        if(use_se){
          const float4 s4 = *(const float4*)&sm->sescale[cc*32 + c4];
          v.x*=s4.x; v.y*=s4.y; v.z*=s4.z; v.w*=s4.w;
        }
        pk.x = bfpack(v.x, v.y); pk.y = bfpack(v.z, v.w);
      }
      *(uint2*)&xs[r*40 + c4] = pk;
    }
    __syncthreads();
    for(int kw=0; kw<Kw; kw++){
      const bfrag Af = *(const bfrag*)&xs[abase + kw*40];
      #pragma unroll
      for(int nt=0; nt<4; nt++){
        const unsigned short* wpp = wp + ((size_t)((cc*Kw + kw)*(Cout>>4) + (by*4 + nt)))*512 + boff;
        const bfrag Bf = *(const bfrag*)wpp;
        acc[nt] = __builtin_amdgcn_mfma_f32_16x16x32_bf16(Af, Bf, acc[nt], 0, 0, 0);
      }
    }
  }
  __syncthreads();
  float* part = (float*)xs;   // [4 wv][64 co][2]
  const int t_base = t0 + wv*16 + q*4;
  #pragma unroll
  for(int nt=0; nt<4; nt++){
    const int co = co0 + nt*16 + m;
    const float bv = bias[co];
    float s1 = 0.f, s2 = 0.f;
    #pragma unroll
    for(int r=0;r<4;r++){
      const float v = acc[nt][r] + bv;
      y[((size_t)b*T_ + t_base + r)*Cout + co] = v;
      s1 += v; s2 += v*v;
    }
    s1 += __shfl_xor(s1, 16); s1 += __shfl_xor(s1, 32);
    s2 += __shfl_xor(s2, 16); s2 += __shfl_xor(s2, 32);
    if(q==0){ part[(wv*64 + nt*16 + m)*2+0] = s1; part[(wv*64 + nt*16 + m)*2+1] = s2; }
  }
  __syncthreads();
  if(tid < 64){
    float a1=0.f, a2=0.f;
    #pragma unroll
    for(int w2i=0; w2i<4; w2i++){ a1 += part[(w2i*64+tid)*2+0]; a2 += part[(w2i*64+tid)*2+1]; }
    atomicAdd(&bnacc[co0 + tid], a1);
    atomicAdd(&bnacc[Cout + co0 + tid], a2);
  }
}

// ---- BN + gelu (writes activated y) + per-(b,c) t-sum accum
__device__ __forceinline__ void bn_act_body(int b, int chunk, char* smemraw,
    float* __restrict__ y, const float* __restrict__ bnacc,
    const float* __restrict__ gw, const float* __restrict__ bw,
    float* __restrict__ mean_acc, int C, int write_y)
{
  const int t0 = chunk*128, tid = threadIdx.x;
  const int c = tid & (C-1), part = tid / C, np = 256 / C;
  const float cnt = (float)(B_*T_);
  const float mm = bnacc[c]/cnt;
  const float var = bnacc[C+c]/cnt - mm*mm;
  const float sc = gw[c]/sqrtf(var+1e-3f);
  const float sh = bw[c] - mm*sc;
  float s = 0.f;
  for(int t=t0+part; t<t0+128; t+=np){
    const size_t off = ((size_t)b*T_ + t)*C + c;
    float v = y[off];
    v = gelu_(v*sc + sh);
    if(write_y) y[off] = v;
    s += v;
  }
  float* rs = (float*)smemraw;
  if(np > 1){
    rs[tid]=s;
    __syncthreads();
    if(part==0) s += rs[tid+C];
  }
  if(part==0) atomicAdd(&mean_acc[b*C+c], s);
}

// ---- SE (mean_in holds t-SUMS; scaled by 1/T here)
__device__ __forceinline__ void se_body(int b, char* smemraw,
    const float* __restrict__ mean_in, const float* __restrict__ w1, const float* __restrict__ w2,
    float* __restrict__ scale, int C, int R)
{
  struct SE { float ms[256]; float hs2[16]; };
  SE* sm = (SE*)smemraw;
  const int tid=threadIdx.x;
  if(tid<C) sm->ms[tid]=mean_in[b*C+tid]*(1.f/(float)T_);
  __syncthreads();
  if(tid<R){ float s=0; for(int k=0;k<C;k++) s+=sm->ms[k]*w1[k*R+tid]; sm->hs2[tid]=fmaxf(s,0.f); }
  __syncthreads();
  if(tid<C){ float s=0; for(int k=0;k<R;k++) s+=sm->hs2[k]*w2[k*C+tid]; scale[b*C+tid]=sig_(s); }
}

// ================================================================ kernels

__global__ __launch_bounds__(256) void mega0_kernel(
    const float* c1w, const float* c2w, const float* c3w,
    unsigned short* wp1, unsigned short* wp2, unsigned short* wp3,
    const float* x, const float* kw1, const float* kb1, float* axT)
{
  __shared__ __align__(16) char sm[16*68*4 + 64*16*4];
  const int bid = blockIdx.x;
  if(bid < 1280) prepack_body(bid, c1w, c2w, c3w, wp1, wp2, wp3);
  else ax_body(bid-1280, sm, x, kw1, kb1, axT);
}

// ---- LSTM scan: isolated, 2 waves per batch (R10 measured-452 configuration)
__global__ __launch_bounds__(128, 1) void lstm_kernel(
    const float* __restrict__ axT, const float* __restrict__ w1,
    const float* __restrict__ w2, const float* __restrict__ b2,
    float* __restrict__ hidden)
{
  __shared__ float hs[2][148];
  const int b = blockIdx.x, tid = threadIdx.x;
  const int l = tid & 63, wv = tid >> 6;
  const int j = l >> 2, g = l & 3;
  const int hi = wv*64 + l;

  v2f w1hv[16];
  #pragma unroll
  for(int q=0;q<16;q++){
    w1hv[q].x = w1[(64 + g*32 + 2*q)*KH_ + j];
    w1hv[q].y = w1[(64 + g*32 + 2*q + 1)*KH_ + j];
  }
  v2f w2if[16], w2go[16];
  #pragma unroll
  for(int k=0;k<16;k++){
    w2if[k].x = w2[k*512 + hi];       w2if[k].y = w2[k*512 + 128 + hi];
    w2go[k].x = w2[k*512 + 256 + hi]; w2go[k].y = w2[k*512 + 384 + hi];
  }
  v2f bif, bgo;
  bif.x = b2[hi]; bif.y = b2[128+hi]; bgo.x = b2[256+hi]; bgo.y = b2[384+hi];

  for(int i=tid;i<2*148;i+=128) ((float*)hs)[i]=0.f;
  float c = 0.f;
  const float* axr = axT + ((size_t)b*16 + j)*1024;
  float* hb = hidden + (size_t)b*T_*H_;
  const int hwi = (hi>>5)*36 + (hi&31);
  float4 axA = *(const float4*)&axr[0];
  float4 axB = *(const float4*)&axr[4];
  __syncthreads();

#define LSTM_STEP(tt, axv, RB) { \
    const float* hsr = hs[RB]; \
    float* hsw = hs[1-(RB)]; \
    v2f ap0=(v2f)(0.f), ap1=(v2f)(0.f), ap2=(v2f)(0.f), ap3=(v2f)(0.f); \
    { const float4 hv = *(const float4*)&hsr[g*36 + 0];  ap0 += ((v2f){hv.x,hv.y})*w1hv[0]  + ((v2f){hv.z,hv.w})*w1hv[1]; } \
    { const float4 hv = *(const float4*)&hsr[g*36 + 4];  ap1 += ((v2f){hv.x,hv.y})*w1hv[2]  + ((v2f){hv.z,hv.w})*w1hv[3]; } \
    { const float4 hv = *(const float4*)&hsr[g*36 + 8];  ap2 += ((v2f){hv.x,hv.y})*w1hv[4]  + ((v2f){hv.z,hv.w})*w1hv[5]; } \
    { const float4 hv = *(const float4*)&hsr[g*36 + 12]; ap3 += ((v2f){hv.x,hv.y})*w1hv[6]  + ((v2f){hv.z,hv.w})*w1hv[7]; } \
    { const float4 hv = *(const float4*)&hsr[g*36 + 16]; ap0 += ((v2f){hv.x,hv.y})*w1hv[8]  + ((v2f){hv.z,hv.w})*w1hv[9]; } \
    { const float4 hv = *(const float4*)&hsr[g*36 + 20]; ap1 += ((v2f){hv.x,hv.y})*w1hv[10] + ((v2f){hv.z,hv.w})*w1hv[11]; } \
    { const float4 hv = *(const float4*)&hsr[g*36 + 24]; ap2 += ((v2f){hv.x,hv.y})*w1hv[12] + ((v2f){hv.z,hv.w})*w1hv[13]; } \
    { const float4 hv = *(const float4*)&hsr[g*36 + 28]; ap3 += ((v2f){hv.x,hv.y})*w1hv[14] + ((v2f){hv.z,hv.w})*w1hv[15]; } \
    const v2f apt = (ap0+ap1)+(ap2+ap3); \
    float a = apt.x + apt.y; \
    a += QPERM_XOR1(a); \
    a += QPERM_XOR2(a); \
    a += (axv); \
    const float g1 = a * sig_(a); \
    v2f aIF = bif, aGO = bgo; \
    _Pragma("unroll") \
    for(int k=0;k<16;k++){ \
      const float gk = __int_as_float(__builtin_amdgcn_readlane(__float_as_int(g1), 4*k)); \
      v2f gk2; gk2.x=gk; gk2.y=gk; \
      aIF += gk2 * w2if[k]; \
      aGO += gk2 * w2go[k]; \
    } \
    const float si = sig_(aIF.x); \
    const float sf = sig_(aIF.y); \
    const float tg = tanh_(aGO.x); \
    const float so = sig_(aGO.y); \
    c = sf*c + si*tg; \
    const float h = so * tanh_(c); \
    hsw[hwi] = h; \
    hb[(size_t)(tt)*H_ + hi] = h; \
    LDS_BARRIER(); \
  }

  for(int t0=0;t0<T_;t0+=4){
    const int tl = (t0+8 < 1020) ? (t0+8) : 1020;
    const float4 axC = *(const float4*)&axr[tl];
    LSTM_STEP(t0+0, axA.x, 0)
    LSTM_STEP(t0+1, axA.y, 1)
    LSTM_STEP(t0+2, axA.z, 0)
    LSTM_STEP(t0+3, axA.w, 1)
    axA = axB; axB = axC;
  }
#undef LSTM_STEP
}

// D2: conv1 (1024) + norm+bf16split (4096)
__global__ __launch_bounds__(256) void megaA_kernel(
    const float* x, const unsigned short* wp1, const float* c1b, float* y1, float* bn1,
    const float* hidden, unsigned short* hnhi, unsigned short* hnlo)
{
  __shared__ __align__(16) char sm[sizeof(ConvS)];
  const int bid = blockIdx.x;
  if(bid < 1024) conv_body(bid&15, (bid>>4)&1, bid>>5, sm, x, wp1, c1b,
                           nullptr, nullptr, nullptr, 0, y1, bn1, F_, C1_, 8);
  else norm_body(bid-1024, hidden, hnhi, hnlo);
}

// D3: s (512) + bn_act1 (256)
__global__ __launch_bounds__(256) void megaB_kernel(
    const unsigned short* hnhi, const unsigned short* hnlo, double* rowsum, double* psum,
    float* y1, const float* bn1, const float* g1w, const float* b1w, float* se1_in)
{
  __shared__ __align__(16) char sm[sizeof(SS)];
  const int bid = blockIdx.x;
  if(bid < 512) s_body(bid, sm, hnhi, hnlo, rowsum, psum);
  else { const int cb = bid-512; bn_act_body(cb>>3, cb&7, sm, y1, bn1, g1w, b1w, se1_in, C1_, 1); }
}

// D4: cluster (32) + conv2 w/ inline SE1 (2048)
__global__ __launch_bounds__(256) void megaC_kernel(
    const double* rowsum, const double* psum, const float* hidden, float* corr, int* cuts,
    const float* y1, const unsigned short* wp2, const float* c2b,
    const float* se1_in, const float* s1w1, const float* s1w2,
    float* y2, float* bn2)
{
  __shared__ __align__(16) char sm[sizeof(CS) > sizeof(ConvS) ? sizeof(CS) : sizeof(ConvS)];
  const int bid = blockIdx.x;
  if(bid < 32) cluster_body(bid, sm, rowsum, psum, hidden, corr, cuts);
  else {
    const int cb = bid - 32;
    conv_body(cb&15, (cb>>4)&3, cb>>6, sm, y1, wp2, c2b,
              se1_in, s1w1, s1w2, C1_/16, y2, bn2, C1_, C2_, 5);
  }
}

// D5: head1 (32) + bn_act2 (256)
__global__ __launch_bounds__(256) void megaD_kernel(
    const float* corr, const float* hidden, const float* eps_z, const float* eps_cat,
    const float* mu_w, const float* mu_b, const float* std_w, const float* std_b,
    const float* muc_w, const float* muc_b, const float* stdc_w, const float* stdc_b,
    float* out_mu, float* out_std, float* out_muc, float* out_stdc, float* x1,
    float* y2, const float* bn2, const float* g2w, const float* b2w, float* se2_in)
{
  __shared__ __align__(16) char sm[1536];
  const int bid = blockIdx.x;
  if(bid < 32) head1_body(bid, sm, corr, hidden, eps_z, eps_cat, mu_w, mu_b, std_w, std_b,
                          muc_w, muc_b, stdc_w, stdc_b, out_mu, out_std, out_muc, out_stdc, x1);
  else { const int cb = bid-32; bn_act_body(cb>>3, cb&7, sm, y2, bn2, g2w, b2w, se2_in, C2_, 1); }
}

// D6: conv3 w/ inline SE2 (1024)
__global__ __launch_bounds__(256) void conv3_kernel(
    const float* y2, const unsigned short* wp3, const float* c3b,
    const float* se2_in, const float* s2w1, const float* s2w2,
    float* y3, float* bn3)
{
  __shared__ __align__(16) char sm[sizeof(ConvS)];
  const int bid = blockIdx.x;
  conv_body(bid&15, (bid>>4)&1, bid>>5, sm, y2, wp3, c3b,
            se2_in, s2w1, s2w2, C2_/16, y3, bn3, C2_, C3_, 3);
}

// D7: bn_act3 (256, t-sums only)
__global__ __launch_bounds__(256) void bn3_kernel(
    float* y3, const float* bn3, const float* g3w, const float* b3w, float* x2)
{
  __shared__ __align__(16) char sm[1024];
  const int bid = blockIdx.x;
  bn_act_body(bid>>3, bid&7, sm, y3, bn3, g3w, b3w, x2, C3_, 0);
}

// D8: final fc + log_softmax (x2 holds t-sums)
__global__ __launch_bounds__(64) void head2_kernel(
    const float* __restrict__ x1, const float* __restrict__ x2,
    const float* __restrict__ fcw, const float* __restrict__ fcb, float* __restrict__ outls)
{
  const int b=blockIdx.x, tid=threadIdx.x;
  __shared__ float xa[256]; __shared__ float lg[NC_];
  for(int k=tid;k<256;k+=64) xa[k] = (k<128)? x1[b*128+k] : x2[b*128+(k-128)]*(1.f/(float)T_);
  __syncthreads();
  if(tid<NC_){
    float s = fcb[tid];
    for(int k=0;k<256;k++) s += xa[k]*fcw[k*NC_+tid];
    lg[tid]=s;
  }
  __syncthreads();
  if(tid==0){
    float mx=lg[0];
    for(int q=1;q<NC_;q++) mx=fmaxf(mx,lg[q]);
    float se=0;
    for(int q=0;q<NC_;q++) se += __expf(lg[q]-mx);
    const float lse = logf(se)+mx;
    for(int q=0;q<NC_;q++) outls[b*NC_+q] = lg[q]-lse;
  }
}

// ================================================================ launch
extern "C" void kernel_launch(void* const* d_in, const int* in_sizes, int n_in,
                              void* d_out, int out_size, void* d_ws, size_t ws_size,
                              hipStream_t stream) {
  (void)in_sizes; (void)n_in; (void)out_size; (void)ws_size;
  const float* x        = (const float*)d_in[0];
  const float* eps_z    = (const float*)d_in[1];
  const float* eps_cat  = (const float*)d_in[2];
  const float* kan_w1   = (const float*)d_in[3];
  const float* kan_b1   = (const float*)d_in[4];
  const float* kan_w2   = (const float*)d_in[5];
  const float* kan_b2   = (const float*)d_in[6];
  const float* conv1_w  = (const float*)d_in[7];
  const float* conv1_b  = (const float*)d_in[8];
  const float* conv2_w  = (const float*)d_in[9];
  const float* conv2_b  = (const float*)d_in[10];
  const float* conv3_w  = (const float*)d_in[11];
  const float* conv3_b  = (const float*)d_in[12];
  const float* bn1_g    = (const float*)d_in[13];
  const float* bn1_b    = (const float*)d_in[14];
  const float* bn2_g    = (const float*)d_in[15];
  const float* bn2_b    = (const float*)d_in[16];
  const float* bn3_g    = (const float*)d_in[17];
  const float* bn3_b    = (const float*)d_in[18];
  const float* se1_w1   = (const float*)d_in[19];
  const float* se1_w2   = (const float*)d_in[20];
  const float* se2_w1   = (const float*)d_in[21];
  const float* se2_w2   = (const float*)d_in[22];
  const float* fc_mu_w  = (const float*)d_in[23];
  const float* fc_mu_b  = (const float*)d_in[24];
  const float* fc_std_w = (const float*)d_in[25];
  const float* fc_std_b = (const float*)d_in[26];
  const float* fc_muc_w = (const float*)d_in[27];
  const float* fc_muc_b = (const float*)d_in[28];
  const float* fc_stdc_w= (const float*)d_in[29];
  const float* fc_stdc_b= (const float*)d_in[30];
  const float* fc_w     = (const float*)d_in[31];
  const float* fc_b     = (const float*)d_in[32];

  float* out = (float*)d_out;
  float* out_ls   = out;
  float* out_mu   = out + 320;
  float* out_std  = out + 320 + 4096;
  float* out_muc  = out + 320 + 2*4096;
  float* out_stdc = out + 320 + 3*4096;

  float* ws = (float*)d_ws;
  const size_t SZ_HID = (size_t)B_*T_*H_;
  const size_t SZ_Y1  = (size_t)B_*T_*C1_;
  const size_t SZ_Y2  = (size_t)B_*T_*C2_;
  float*  hidden = ws;                      // [b][t][H] — never aliased
  float*  y1     = hidden + SZ_HID;         // conv1 out; reused as y3 after conv2
  float*  y2     = y1 + SZ_Y1;
  double* rowsum = (double*)(y2 + SZ_Y2);
  double* psum   = rowsum + (size_t)B_*T_;
  float*  corr   = (float*)(psum + (size_t)B_*T_);
  float*  x1     = corr + (size_t)B_*H_;
  float*  bnbuf  = x1 + (size_t)B_*H_;      // zeroed region starts here
  float*  bn1    = bnbuf;
  float*  bn2    = bnbuf + 2*C1_;
  float*  bn3    = bnbuf + 2*C1_ + 2*C2_;
  float*  se1_in = bnbuf + 1024;
  float*  se2_in = se1_in + (size_t)B_*C1_;
  float*  x2     = se2_in + (size_t)B_*C2_;
  int*    cuts   = (int*)(x2 + (size_t)B_*C3_);
  float*  axbuf  = (float*)(cuts + B_);     // axT: B*16*T
  unsigned short* wp1 = (unsigned short*)(axbuf + (size_t)B_*16*T_);
  unsigned short* wp2 = wp1 + (size_t)C1_*F_*8;
  unsigned short* wp3 = wp2 + (size_t)C2_*C1_*5;
  unsigned short* hnhi = wp3 + (size_t)C3_*C2_*3;
  unsigned short* hnlo = hnhi + (size_t)B_*T_*H_;
  float*  y3     = y1;   // y1 dead after D4 (conv2); conv3 (D6) reuses it

  // zero bn accumulators + se/x2 t-sum accumulators
  hipMemsetAsync(bnbuf, 0, (size_t)(1024 + B_*C1_ + B_*C2_ + B_*C3_)*sizeof(float), stream);

  // D0: prepack (1280) + ax (2048)
  mega0_kernel<<<3328, 256, 0, stream>>>(conv1_w, conv2_w, conv3_w, wp1, wp2, wp3,
                                         x, kan_w1, kan_b1, axbuf);
  // D1: lstm — isolated, latency-critical
  lstm_kernel<<<B_, 128, 0, stream>>>(axbuf, kan_w1, kan_w2, kan_b2, hidden);
  // D2: conv1 + norm (writes hn hi/lo bf16 once)
  megaA_kernel<<<1024 + 4096, 256, 0, stream>>>(x, wp1, conv1_b, y1, bn1, hidden, hnhi, hnlo);
  // D3: s (copy-staging) + bn_act1
  megaB_kernel<<<512 + 256, 256, 0, stream>>>(hnhi, hnlo, rowsum, psum,
                                              y1, bn1, bn1_g, bn1_b, se1_in);
  // D4: cluster + conv2 (inline SE1)
  megaC_kernel<<<32 + 2048, 256, 0, stream>>>(rowsum, psum, hidden, corr, cuts,
                                              y1, wp2, conv2_b, se1_in, se1_w1, se1_w2, y2, bn2);
  // D5: head1 + bn_act2
  megaD_kernel<<<32 + 256, 256, 0, stream>>>(corr, hidden, eps_z, eps_cat,
      fc_mu_w, fc_mu_b, fc_std_w, fc_std_b, fc_muc_w, fc_muc_b, fc_stdc_w, fc_stdc_b,
      out_mu, out_std, out_muc, out_stdc, x1,
      y2, bn2, bn2_g, bn2_b, se2_in);
  // D6: conv3 (inline SE2)
  conv3_kernel<<<1024, 256, 0, stream>>>(y2, wp3, conv3_b, se2_in, se2_w1, se2_w2, y3, bn3);
  // D7: bn_act3 (t-sums only)
  bn3_kernel<<<256, 256, 0, stream>>>(y3, bn3, bn3_g, bn3_b, x2);
  // D8: final head
  head2_kernel<<<B_, 64, 0, stream>>>(x1, x2, fc_w, fc_b, out_ls);
}